// Round 2
// baseline (1027.315 us; speedup 1.0000x reference)
//
#include <hip/hip_runtime.h>
#include <hip/hip_bf16.h>
#include <math.h>

// B=32 graphs, N=256 nodes/graph, D=128.
#define DD   128
#define NPG  256
#define NGR  32
#define TTOT 8192
#define LOG2E  1.4426950408889634f
#define LOG2E2 2.8853900817779268f   // 2*log2(e)
#define KSTRIDE 264                   // LDS floats per transposed key row
#define SSTR    268                   // spartS row stride
#define H2A(j)  ((j) + (((j)>>5)<<3))   // stagger: chunk base -> bank chunk*8
#define PAD16(j) ((j) + (((j)>>4)<<2))  // q/v pad: d -> d + (d>>4)*4

__device__ __forceinline__ float dot4(float4 a, float4 b){
  return a.x*b.x + a.y*b.y + a.z*b.z + a.w*b.w;
}
// ---- DPP cross-lane (VALU pipe; keeps ds_bpermute off critical chains) ----
template<int CTRL, int RMASK>
__device__ __forceinline__ float upd_f(float oldv, float x){
  return __int_as_float(__builtin_amdgcn_update_dpp(
      __float_as_int(oldv), __float_as_int(x), CTRL, RMASK, 0xf, false));
}
__device__ __forceinline__ float dpp_xor1(float x){
  return __int_as_float(__builtin_amdgcn_mov_dpp(__float_as_int(x), 0xB1, 0xf, 0xf, false));
}
__device__ __forceinline__ float dpp_xor2(float x){
  return __int_as_float(__builtin_amdgcn_mov_dpp(__float_as_int(x), 0x4E, 0xf, 0xf, false));
}
__device__ __forceinline__ float quad_sum_dpp(float x){
  float s = x + dpp_xor1(x);
  return s + dpp_xor2(s);
}
__device__ __forceinline__ float dpp_wave_sum(float x){
  x += upd_f<0x111,0xf>(0.f, x);   // row_shr:1
  x += upd_f<0x112,0xf>(0.f, x);   // row_shr:2
  x += upd_f<0x114,0xf>(0.f, x);   // row_shr:4
  x += upd_f<0x118,0xf>(0.f, x);   // row_shr:8
  x += upd_f<0x142,0xa>(0.f, x);   // row_bcast15
  x += upd_f<0x143,0xc>(0.f, x);   // row_bcast31
  return __uint_as_float(__builtin_amdgcn_readlane(__float_as_uint(x), 63));
}
__device__ __forceinline__ float dpp_wave_max(float x){
  const float NI = -INFINITY;
  x = fmaxf(x, upd_f<0x111,0xf>(NI, x));
  x = fmaxf(x, upd_f<0x112,0xf>(NI, x));
  x = fmaxf(x, upd_f<0x114,0xf>(NI, x));
  x = fmaxf(x, upd_f<0x118,0xf>(NI, x));
  x = fmaxf(x, upd_f<0x142,0xa>(NI, x));
  x = fmaxf(x, upd_f<0x143,0xc>(NI, x));
  return __uint_as_float(__builtin_amdgcn_readlane(__float_as_uint(x), 63));
}
__device__ __forceinline__ float sigfast(float x){
  return __builtin_amdgcn_rcpf(1.f + __builtin_amdgcn_exp2f(-x*LOG2E));
}
__device__ __forceinline__ float tanhfast(float y){
  return 1.f - 2.f*__builtin_amdgcn_rcpf(1.f + __builtin_amdgcn_exp2f(y*LOG2E2));
}

// ---------------- Kernel 1: parallel precompute (R9/R12 SCALAR version) ----------------
// SCALAR mm_tile accumulation order is part of the validated-numerics contract
// (R10's float4 reorder flipped a near-tie argmax -> tour divergence). DO NOT vectorize.
// keysE[d][n] = exp(2 * l2norm(relu(emb@Wk1.T+bk1)@Wk2.T+bk2)[n][d])  [128][8192] TRANSPOSED
// gi_all = emb@W_ih.T + b_ih                                          [8192,384]

__device__ __forceinline__ void load_w128(float* Ws, const float* __restrict__ W, int t){
  const float4* src = (const float4*)W;
  #pragma unroll
  for (int m=0;m<16;m++){
    int idx = m*256+t; int r = idx>>5, c4 = idx&31;
    float4 val = src[idx];
    float* dst = &Ws[r*129 + c4*4];
    dst[0]=val.x; dst[1]=val.y; dst[2]=val.z; dst[3]=val.w;
  }
}

__device__ __forceinline__ void mm_tile(const float* __restrict__ inS, const float* __restrict__ Ws,
                                        float acc[4][4], int jg, int ng){
  #pragma unroll
  for(int r=0;r<4;r++)
    #pragma unroll
    for(int c=0;c<4;c++) acc[r][c]=0.f;
  #pragma unroll 4
  for (int k=0;k<128;k++){
    float w[4], x[4];
    #pragma unroll
    for (int r=0;r<4;r++) w[r] = Ws[(jg*4+r)*129+k];
    #pragma unroll
    for (int c=0;c<4;c++) x[c] = inS[(ng*4+c)*129+k];
    #pragma unroll
    for (int r=0;r<4;r++)
      #pragma unroll
      for (int c=0;c<4;c++) acc[r][c] += w[r]*x[c];
  }
}

__global__ __launch_bounds__(256) void precompute_kernel(
    const float* __restrict__ emb,
    const float* __restrict__ Wk1, const float* __restrict__ bk1,
    const float* __restrict__ Wk2, const float* __restrict__ bk2,
    const float* __restrict__ Wih, const float* __restrict__ bih,
    float* __restrict__ keysE, float* __restrict__ giall)
{
  __shared__ __align__(16) float xs[32*129];
  __shared__ __align__(16) float Ws[128*129];
  __shared__ __align__(16) float hs[32*129];
  __shared__ __align__(16) float os[32*129];
  __shared__ float nrm[32];
  const int t  = threadIdx.x;
  const int n0 = blockIdx.x * 32;
  const int ng = t & 7, jg = t >> 3;

  {
    const float4* src = (const float4*)emb + (size_t)n0*32;
    #pragma unroll
    for (int m=0;m<4;m++){
      int idx = m*256+t; int n = idx>>5, c4 = idx&31;
      float4 val = src[idx];
      float* dst = &xs[n*129 + c4*4];
      dst[0]=val.x; dst[1]=val.y; dst[2]=val.z; dst[3]=val.w;
    }
  }
  load_w128(Ws, Wk1, t);
  __syncthreads();
  {
    float acc[4][4];
    mm_tile(xs, Ws, acc, jg, ng);
    #pragma unroll
    for (int r=0;r<4;r++){
      float bb = bk1[jg*4+r];
      #pragma unroll
      for (int c=0;c<4;c++) hs[(ng*4+c)*129 + jg*4+r] = fmaxf(acc[r][c]+bb, 0.f);
    }
  }
  __syncthreads();
  load_w128(Ws, Wk2, t);
  __syncthreads();
  {
    float acc[4][4];
    mm_tile(hs, Ws, acc, jg, ng);
    #pragma unroll
    for (int r=0;r<4;r++){
      float bb = bk2[jg*4+r];
      #pragma unroll
      for (int c=0;c<4;c++) os[(ng*4+c)*129 + jg*4+r] = acc[r][c]+bb;
    }
  }
  __syncthreads();
  if (t<32){
    float ss=0.f;
    for (int j=0;j<128;j++){ float x = os[t*129+j]; ss += x*x; }
    nrm[t] = fmaxf(sqrtf(ss), 1e-12f);
  }
  __syncthreads();
  // transposed E-keys: keysE[d][n] = exp(2*K)
  #pragma unroll
  for (int m=0;m<16;m++){
    int idx = m*256+t; int nl = idx & 31, d = idx >> 5;
    float kk = os[nl*129 + d] / nrm[nl];
    keysE[(size_t)d*TTOT + n0 + nl] = __builtin_amdgcn_exp2f(kk * LOG2E2);
  }
  for (int c=0;c<3;c++){
    __syncthreads();
    load_w128(Ws, Wih + c*16384, t);
    __syncthreads();
    float acc[4][4];
    mm_tile(xs, Ws, acc, jg, ng);
    #pragma unroll
    for (int r=0;r<4;r++){
      float bb = bih[c*128 + jg*4+r];
      #pragma unroll
      for (int cc=0;cc<4;cc++)
        giall[(size_t)(n0 + ng*4+cc)*384 + c*128 + jg*4 + r] = acc[r][cc] + bb;
    }
  }
}

// ---------------- Kernel 2: sequential decode ----------------
// 32 blocks x 512 threads; 255 steps; FOUR barriers/step.
// R14 = R13 minus the giall L2-warm (isolated regression suspect: warm's
// cross-XCD dirty-line sweep showed up as WRITE_SIZE +320KB and ~+87us).
// Kept from R13 (all bit-identical arithmetic):
//  - col<->node maps in per-wave registers (lane L owns entries 4L..4L+3):
//    lookups are cndmask+readlane (~30cy) instead of 120cy ds_read on the
//    combine->gi critical chain. Wave-private, redundantly updated.
//  - gi prefetch issued right after besti/node, BEFORE the es/S/lp tail.
//  - score/combine LDS reads exec-masked to cols < V (invalid cols were
//    already forced -inf; bit-identical) -> average LDS burst halves.
//  - tours/lp buffered in LDS, dumped once after the loop.
//  - lane's own h[g] kept in a register across steps (z*hg bit-identical).

__global__ __launch_bounds__(512, 2) void decode_kernel(
    const float* __restrict__ emb,
    const float* __restrict__ keysE, const float* __restrict__ giall,
    const float* __restrict__ Whh, const float* __restrict__ bhh,
    const float* __restrict__ Wq1, const float* __restrict__ bq1,
    const float* __restrict__ Wq2, const float* __restrict__ bq2,
    const float* __restrict__ v,   const float* __restrict__ Wh,
    const float* __restrict__ bh,  const int* __restrict__ start_nodes,
    float* __restrict__ tours_o, float* __restrict__ lp_o)
{
  __shared__ __align__(16) float keys_s[128*KSTRIDE];  // 132 KB, transposed E-keys
  __shared__ __align__(16) float h_s[2][160];          // staggered (H2A)
  __shared__ __align__(16) float qh_s[160];            // staggered (H2A)
  __shared__ __align__(16) float q_s[160];             // PAD16 (raw q), also gctx scratch
  __shared__ __align__(16) float v_sp[160];            // PAD16 layout, -2*v
  __shared__ __align__(16) float spartS[8*SSTR];       // score partials (+init scratch)
  __shared__ float red2[8];
  __shared__ float tour_s[256];
  __shared__ float lp_s[256];

  const int t = threadIdx.x;
  const int b = blockIdx.x;
  const int g  = t >> 2, s3 = t & 3;   // 128 groups x 4 lanes (matvec)
  const int w  = t >> 6, L  = t & 63;
  const int oct = L & 7, dgrp = L >> 3; // score: col-octet, dim-group

  // register weights: Whh rows g,128+g,256+g (chunk s3*32); Wq1/Wq2 row g
  float4 whh4[3][8], wq14[8], wq24[8];
  {
    const float4* w0  = (const float4*)(Whh + (size_t)(g      )*128 + s3*32);
    const float4* w1  = (const float4*)(Whh + (size_t)(128 + g)*128 + s3*32);
    const float4* w2  = (const float4*)(Whh + (size_t)(256 + g)*128 + s3*32);
    const float4* q1p = (const float4*)(Wq1 + (size_t)g*128 + s3*32);
    const float4* q2p = (const float4*)(Wq2 + (size_t)g*128 + s3*32);
    #pragma unroll
    for (int i=0;i<8;i++){
      whh4[0][i]=w0[i]; whh4[1][i]=w1[i]; whh4[2][i]=w2[i];
      wq14[i]=q1p[i];   wq24[i]=q2p[i];
    }
  }
  const float br = bhh[g], bz = bhh[128+g], bn = bhh[256+g];
  const float b1g = bq1[g], b2g = bq2[g];

  // per-wave register-distributed col<->node maps: lane L owns 4L..4L+3.
  // (named scalars, cndmask-updated: rule #20, no runtime-indexed arrays)
  int c2n0 = 4*L, c2n1 = 4*L+1, c2n2 = 4*L+2, c2n3 = 4*L+3;
  int n2c0 = 4*L, n2c1 = 4*L+1, n2c2 = 4*L+2, n2c3 = 4*L+3;

  if (t<128) v_sp[PAD16(t)] = -2.f * v[t];
  { // stage transposed E-keys: coalesced per d-row
    #pragma unroll
    for (int m=0;m<16;m++){
      int idx = m*512 + t; int d = idx>>6, q = idx&63;
      *(float4*)(keys_s + d*KSTRIDE + q*4) =
        *(const float4*)(keysE + (size_t)d*TTOT + b*256 + q*4);
    }
  }
  { // graph-context partial sums (4 parts x 64 nodes)
    int d = t & 127, part = t >> 7;
    float a = 0.f;
    const float* base = emb + (size_t)(b*256 + part*64)*128 + d;
    for (int i=0;i<64;i++) a += base[(size_t)i*128];
    spartS[part*128+d] = a;
  }
  int cur = start_nodes[b];
  __syncthreads();
  if (t<128){
    float a = 0.f;
    #pragma unroll
    for (int p=0;p<4;p++) a += spartS[p*128+t];
    q_s[t] = a * (1.f/256.f);          // gctx temp (plain idx, init only)
  }
  __syncthreads();
  if (t<128){ // hidden0 = gctx@Wh.T + bh  (write staggered)
    float a = bh[t];
    const float* wr = Wh + (size_t)t*128;
    for (int k=0;k<128;k++) a += wr[k]*q_s[k];
    h_s[0][H2A(t)] = a;
  }
  { // sv = sum(v)
    float xv = (t<128) ? v[t] : 0.f;
    float tot = dpp_wave_sum(xv);
    if (L==0) red2[w] = tot;
  }
  __syncthreads();
  float sv = 0.f;
  #pragma unroll
  for (int i=0;i<8;i++) sv += red2[i];
  float hg = 0.f;                      // lane's own h[g], lives in a register
  if (s3==0) hg = h_s[0][H2A(g)];

  // gi prefetch for step 0
  float gir=0.f, giz=0.f, gin=0.f;
  if (s3==0){
    const float* gp = giall + (size_t)cur*384 + g;
    gir = gp[0]; giz = gp[128]; gin = gp[256];
  }

  for (int step=0; step<255; step++){
    const int par = step & 1;
    const int V   = 255 - step;          // valid count after removing cur
    const int curl = cur - b*256;

    // ---- register map: px = n2c[curl] (pre-update), ln = c2n[V]; then
    //      swap-remove update c2n[px]=ln, n2c[ln]=px (private per wave) ----
    int selp = (curl&2) ? ((curl&1)?n2c3:n2c2) : ((curl&1)?n2c1:n2c0);
    const int px = __builtin_amdgcn_readlane(selp, curl>>2);
    int selc = (V&2) ? ((V&1)?c2n3:c2n2) : ((V&1)?c2n1:c2n0);
    const int ln = __builtin_amdgcn_readlane(selc, V>>2);
    {
      const bool mp = (L == (px>>2)); const int pq = px & 3;
      c2n0 = (mp && pq==0) ? ln : c2n0;
      c2n1 = (mp && pq==1) ? ln : c2n1;
      c2n2 = (mp && pq==2) ? ln : c2n2;
      c2n3 = (mp && pq==3) ? ln : c2n3;
      const bool ml = (L == (ln>>2)); const int lq = ln & 3;
      n2c0 = (ml && lq==0) ? px : n2c0;
      n2c1 = (ml && lq==1) ? px : n2c1;
      n2c2 = (ml && lq==2) ? px : n2c2;
      n2c3 = (ml && lq==3) ? px : n2c3;
    }

    // ---- swap-remove cur's keys column (waves 2-3; px from own regs) ----
    if (t >= 128 && t < 256){
      int r = t - 128;
      keys_s[r*KSTRIDE + px] = keys_s[r*KSTRIDE + V];
    }
    if (t == 384) tour_s[step] = (float)cur;          // wave 6, LDS only

    // ---- phase A: gh dots + fused GRU -> h_s[par^1] ----
    {
      float a0=0.f,a1=0.f,a2=0.f;
      const float4* hc4 = (const float4*)(h_s[par] + s3*40);
      #pragma unroll
      for (int i=0;i<8;i++){
        float4 hv = hc4[i];
        a0 += dot4(whh4[0][i], hv);
        a1 += dot4(whh4[1][i], hv);
        a2 += dot4(whh4[2][i], hv);
      }
      a0 = quad_sum_dpp(a0);
      a1 = quad_sum_dpp(a1);
      a2 = quad_sum_dpp(a2);
      if (s3==0){
        float r = sigfast(gir + a0 + br);
        float z = sigfast(giz + a1 + bz);
        float n = tanhfast(gin + r*(a2 + bn));
        float hnew = (1.f-z)*n + z*hg;               // z*hg == z*h_s[par][H2A(g)]
        h_s[par^1][H2A(g)] = hnew;
        hg = hnew;
      }
    }
    __syncthreads();                                   // B1

    { // qh = relu(h@Wq1.T + bq1)
      float a=0.f;
      const float4* hc4 = (const float4*)(h_s[par^1] + s3*40);
      #pragma unroll
      for (int i=0;i<8;i++) a += dot4(wq14[i], hc4[i]);
      a = quad_sum_dpp(a);
      if (s3==0) qh_s[H2A(g)] = fmaxf(a + b1g, 0.f);
    }
    __syncthreads();                                   // B2

    { // q_raw = qh@Wq2.T + bq2 (PAD16 store) ; per-wave ssq via DPP
      float a=0.f;
      const float4* qc4 = (const float4*)(qh_s + s3*40);
      #pragma unroll
      for (int i=0;i<8;i++) a += dot4(wq24[i], qc4[i]);
      a = quad_sum_dpp(a);
      float qval = a + b2g;
      if (s3==0) q_s[PAD16(g)] = qval;
      float ssp = (s3==0) ? qval*qval : 0.f;
      float tot = dpp_wave_sum(ssp);
      if (L==0) red2[w] = tot;
    }
    __syncthreads();                                   // B3

    // ---- score: lane covers cols co..co+3; exec-masked to co < V
    //      (co<V implies 32w<V, so whole-wave execz skip is preserved) ----
    {
      const int co = 32*w + oct*4;
      if (co < V){
        float ss = 0.f;
        #pragma unroll
        for (int i=0;i<8;i++) ss += red2[i];
        float rn = 1.f / fmaxf(sqrtf(ss), 1e-12f);
        const float* kbase = keys_s + dgrp*16*KSTRIDE + co;
        const float* qb    = q_s  + dgrp*20;
        const float* vbase = v_sp + dgrp*20;
        float4 acc = {0.f,0.f,0.f,0.f};
        #pragma unroll
        for (int jj=0;jj<16;jj++){
          float eqj = __builtin_amdgcn_exp2f(qb[jj] * rn * LOG2E2);
          float vj  = vbase[jj];
          float4 K = *(const float4*)(kbase + jj*KSTRIDE);
          float r0 = __builtin_amdgcn_rcpf(fmaf(K.x, eqj, 1.f));
          float r1 = __builtin_amdgcn_rcpf(fmaf(K.y, eqj, 1.f));
          float r2 = __builtin_amdgcn_rcpf(fmaf(K.z, eqj, 1.f));
          float r3 = __builtin_amdgcn_rcpf(fmaf(K.w, eqj, 1.f));
          acc.x = fmaf(vj, r0, acc.x);
          acc.y = fmaf(vj, r1, acc.y);
          acc.z = fmaf(vj, r2, acc.z);
          acc.w = fmaf(vj, r3, acc.w);
        }
        *(float4*)(spartS + dgrp*SSTR + co) = acc;
      }
    }
    __syncthreads();                                   // Bs1

    // ---- redundant combine: EVERY wave reduces valid cols; every lane
    //      learns argmax + softmax sum -> no Bs2, no tail round-trip.
    //      spartS reads masked to c0 < V (invalid cols are -inf anyway). ----
    {
      const int c0 = 4*L;
      float sx=0.f, sy=0.f, sz=0.f, sw=0.f;
      if (c0 < V){
        const float* sp = spartS + c0;
        #pragma unroll
        for (int i=0;i<8;i++){
          float4 p = *(const float4*)(sp + i*SSTR);
          sx += p.x; sy += p.y; sz += p.z; sw += p.w;
        }
      }
      float vx = (c0+0 < V) ? sv+sx : -INFINITY;
      float vy = (c0+1 < V) ? sv+sy : -INFINITY;
      float vz = (c0+2 < V) ? sv+sz : -INFINITY;
      float vw = (c0+3 < V) ? sv+sw : -INFINITY;
      float bm = vx; int bc = c0;                 // first-max tie-break
      if (vy > bm){ bm=vy; bc=c0+1; }
      if (vz > bm){ bm=vz; bc=c0+2; }
      if (vw > bm){ bm=vw; bc=c0+3; }
      float m = dpp_wave_max(bm);
      unsigned long long mk = __ballot(bm == m);
      int flane = __ffsll(mk) - 1;                // lowest lane = lowest col
      int besti = __builtin_amdgcn_readlane(bc, flane);
      // node lookup from post-update register map; gi prefetch issued
      // BEFORE the es/S/lp tail so the load overlaps it + next phase A.
      int seln = (besti&2) ? ((besti&1)?c2n3:c2n2) : ((besti&1)?c2n1:c2n0);
      cur = b*256 + __builtin_amdgcn_readlane(seln, besti>>2);
      if (s3==0){   // prefetch next gi (consumed in next phase A)
        const float* gp = giall + (size_t)cur*384 + g;
        gir = gp[0]; giz = gp[128]; gin = gp[256];
      }
      float es = __builtin_amdgcn_exp2f((vx-m)*LOG2E) + __builtin_amdgcn_exp2f((vy-m)*LOG2E)
               + __builtin_amdgcn_exp2f((vz-m)*LOG2E) + __builtin_amdgcn_exp2f((vw-m)*LOG2E);
      float S = dpp_wave_sum(es);
      if (t==320) lp_s[step] = logf(1.f/S + 1e-10f);  // wave 5, LDS only
    }
    // no barrier: next step's keys-swap/phase-A touch no combine-read state;
    // register maps are wave-private.
  }
  if (t==0) tour_s[255] = (float)cur;
  __syncthreads();
  // single coalesced dump of tours + log_probs
  if (t < 256)      tours_o[b*256 + t] = tour_s[t];
  else if (t < 511) lp_o[b*255 + (t-256)] = lp_s[t-256];
}

extern "C" void kernel_launch(void* const* d_in, const int* in_sizes, int n_in,
                              void* d_out, int out_size, void* d_ws, size_t ws_size,
                              hipStream_t stream) {
  const float* emb  = (const float*)d_in[0];
  const int*   startn = (const int*)d_in[1];
  const float* Wq1 = (const float*)d_in[3];  const float* bq1 = (const float*)d_in[4];
  const float* Wq2 = (const float*)d_in[5];  const float* bq2 = (const float*)d_in[6];
  const float* Wk1 = (const float*)d_in[7];  const float* bk1 = (const float*)d_in[8];
  const float* Wk2 = (const float*)d_in[9];  const float* bk2 = (const float*)d_in[10];
  const float* Wih = (const float*)d_in[11]; const float* Whh = (const float*)d_in[12];
  const float* bih = (const float*)d_in[13]; const float* bhh = (const float*)d_in[14];
  const float* v   = (const float*)d_in[15]; const float* Wh  = (const float*)d_in[16];
  const float* bh  = (const float*)d_in[17];

  float* keysE = (float*)d_ws;               // exp(2*keys) TRANSPOSED [128][8192]
  float* giall = keysE + (size_t)TTOT*DD;    // [8192*384]

  float* outp = (float*)d_out;   // tours [32*256] then log_probs [32*255]

  precompute_kernel<<<256, 256, 0, stream>>>(emb, Wk1, bk1, Wk2, bk2, Wih, bih, keysE, giall);
  decode_kernel<<<NGR, 512, 0, stream>>>(emb, keysE, giall, Whh, bhh, Wq1, bq1, Wq2, bq2,
                                         v, Wh, bh, startn, outp, outp + TTOT);
}

// Round 3
// 895.637 us; speedup vs baseline: 1.1470x; 1.1470x over previous
//
#include <hip/hip_runtime.h>
#include <hip/hip_bf16.h>
#include <math.h>

// B=32 graphs, N=256 nodes/graph, D=128.
#define DD   128
#define NPG  256
#define NGR  32
#define TTOT 8192
#define LOG2E  1.4426950408889634f
#define LOG2E2 2.8853900817779268f   // 2*log2(e)
#define KSTRIDE 264                   // LDS floats per transposed key row
#define SSTR    268                   // spartS row stride
#define H2A(j)  ((j) + (((j)>>5)<<3))   // stagger: chunk base -> bank chunk*8
#define PAD16(j) ((j) + (((j)>>4)<<2))  // q/v pad: d -> d + (d>>4)*4

__device__ __forceinline__ float dot4(float4 a, float4 b){
  return a.x*b.x + a.y*b.y + a.z*b.z + a.w*b.w;
}
// ---- DPP cross-lane (VALU pipe; keeps ds_bpermute off critical chains) ----
template<int CTRL, int RMASK>
__device__ __forceinline__ float upd_f(float oldv, float x){
  return __int_as_float(__builtin_amdgcn_update_dpp(
      __float_as_int(oldv), __float_as_int(x), CTRL, RMASK, 0xf, false));
}
__device__ __forceinline__ float dpp_xor1(float x){
  return __int_as_float(__builtin_amdgcn_mov_dpp(__float_as_int(x), 0xB1, 0xf, 0xf, false));
}
__device__ __forceinline__ float dpp_xor2(float x){
  return __int_as_float(__builtin_amdgcn_mov_dpp(__float_as_int(x), 0x4E, 0xf, 0xf, false));
}
__device__ __forceinline__ float quad_sum_dpp(float x){
  float s = x + dpp_xor1(x);
  return s + dpp_xor2(s);
}
__device__ __forceinline__ float dpp_wave_sum(float x){
  x += upd_f<0x111,0xf>(0.f, x);   // row_shr:1
  x += upd_f<0x112,0xf>(0.f, x);   // row_shr:2
  x += upd_f<0x114,0xf>(0.f, x);   // row_shr:4
  x += upd_f<0x118,0xf>(0.f, x);   // row_shr:8
  x += upd_f<0x142,0xa>(0.f, x);   // row_bcast15
  x += upd_f<0x143,0xc>(0.f, x);   // row_bcast31
  return __uint_as_float(__builtin_amdgcn_readlane(__float_as_uint(x), 63));
}
__device__ __forceinline__ float dpp_wave_max(float x){
  const float NI = -INFINITY;
  x = fmaxf(x, upd_f<0x111,0xf>(NI, x));
  x = fmaxf(x, upd_f<0x112,0xf>(NI, x));
  x = fmaxf(x, upd_f<0x114,0xf>(NI, x));
  x = fmaxf(x, upd_f<0x118,0xf>(NI, x));
  x = fmaxf(x, upd_f<0x142,0xa>(NI, x));
  x = fmaxf(x, upd_f<0x143,0xc>(NI, x));
  return __uint_as_float(__builtin_amdgcn_readlane(__float_as_uint(x), 63));
}
__device__ __forceinline__ float sigfast(float x){
  return __builtin_amdgcn_rcpf(1.f + __builtin_amdgcn_exp2f(-x*LOG2E));
}
__device__ __forceinline__ float tanhfast(float y){
  return 1.f - 2.f*__builtin_amdgcn_rcpf(1.f + __builtin_amdgcn_exp2f(y*LOG2E2));
}

// ---------------- Kernel 1: parallel precompute (R9/R12 SCALAR version) ----------------
// SCALAR mm_tile accumulation order is part of the validated-numerics contract
// (R10's float4 reorder flipped a near-tie argmax -> tour divergence). DO NOT vectorize.
// keysE[d][n] = exp(2 * l2norm(relu(emb@Wk1.T+bk1)@Wk2.T+bk2)[n][d])  [128][8192] TRANSPOSED
// gi_all = emb@W_ih.T + b_ih                                          [8192,384]

__device__ __forceinline__ void load_w128(float* Ws, const float* __restrict__ W, int t){
  const float4* src = (const float4*)W;
  #pragma unroll
  for (int m=0;m<16;m++){
    int idx = m*256+t; int r = idx>>5, c4 = idx&31;
    float4 val = src[idx];
    float* dst = &Ws[r*129 + c4*4];
    dst[0]=val.x; dst[1]=val.y; dst[2]=val.z; dst[3]=val.w;
  }
}

__device__ __forceinline__ void mm_tile(const float* __restrict__ inS, const float* __restrict__ Ws,
                                        float acc[4][4], int jg, int ng){
  #pragma unroll
  for(int r=0;r<4;r++)
    #pragma unroll
    for(int c=0;c<4;c++) acc[r][c]=0.f;
  #pragma unroll 4
  for (int k=0;k<128;k++){
    float w[4], x[4];
    #pragma unroll
    for (int r=0;r<4;r++) w[r] = Ws[(jg*4+r)*129+k];
    #pragma unroll
    for (int c=0;c<4;c++) x[c] = inS[(ng*4+c)*129+k];
    #pragma unroll
    for (int r=0;r<4;r++)
      #pragma unroll
      for (int c=0;c<4;c++) acc[r][c] += w[r]*x[c];
  }
}

__global__ __launch_bounds__(256) void precompute_kernel(
    const float* __restrict__ emb,
    const float* __restrict__ Wk1, const float* __restrict__ bk1,
    const float* __restrict__ Wk2, const float* __restrict__ bk2,
    const float* __restrict__ Wih, const float* __restrict__ bih,
    float* __restrict__ keysE, float* __restrict__ giall)
{
  __shared__ __align__(16) float xs[32*129];
  __shared__ __align__(16) float Ws[128*129];
  __shared__ __align__(16) float hs[32*129];
  __shared__ __align__(16) float os[32*129];
  __shared__ float nrm[32];
  const int t  = threadIdx.x;
  const int n0 = blockIdx.x * 32;
  const int ng = t & 7, jg = t >> 3;

  {
    const float4* src = (const float4*)emb + (size_t)n0*32;
    #pragma unroll
    for (int m=0;m<4;m++){
      int idx = m*256+t; int n = idx>>5, c4 = idx&31;
      float4 val = src[idx];
      float* dst = &xs[n*129 + c4*4];
      dst[0]=val.x; dst[1]=val.y; dst[2]=val.z; dst[3]=val.w;
    }
  }
  load_w128(Ws, Wk1, t);
  __syncthreads();
  {
    float acc[4][4];
    mm_tile(xs, Ws, acc, jg, ng);
    #pragma unroll
    for (int r=0;r<4;r++){
      float bb = bk1[jg*4+r];
      #pragma unroll
      for (int c=0;c<4;c++) hs[(ng*4+c)*129 + jg*4+r] = fmaxf(acc[r][c]+bb, 0.f);
    }
  }
  __syncthreads();
  load_w128(Ws, Wk2, t);
  __syncthreads();
  {
    float acc[4][4];
    mm_tile(hs, Ws, acc, jg, ng);
    #pragma unroll
    for (int r=0;r<4;r++){
      float bb = bk2[jg*4+r];
      #pragma unroll
      for (int c=0;c<4;c++) os[(ng*4+c)*129 + jg*4+r] = acc[r][c]+bb;
    }
  }
  __syncthreads();
  if (t<32){
    float ss=0.f;
    for (int j=0;j<128;j++){ float x = os[t*129+j]; ss += x*x; }
    nrm[t] = fmaxf(sqrtf(ss), 1e-12f);
  }
  __syncthreads();
  // transposed E-keys: keysE[d][n] = exp(2*K)
  #pragma unroll
  for (int m=0;m<16;m++){
    int idx = m*256+t; int nl = idx & 31, d = idx >> 5;
    float kk = os[nl*129 + d] / nrm[nl];
    keysE[(size_t)d*TTOT + n0 + nl] = __builtin_amdgcn_exp2f(kk * LOG2E2);
  }
  for (int c=0;c<3;c++){
    __syncthreads();
    load_w128(Ws, Wih + c*16384, t);
    __syncthreads();
    float acc[4][4];
    mm_tile(xs, Ws, acc, jg, ng);
    #pragma unroll
    for (int r=0;r<4;r++){
      float bb = bih[c*128 + jg*4+r];
      #pragma unroll
      for (int cc=0;cc<4;cc++)
        giall[(size_t)(n0 + ng*4+cc)*384 + c*128 + jg*4 + r] = acc[r][cc] + bb;
    }
  }
}

// ---------------- Kernel 2: sequential decode ----------------
// 32 blocks x 512 threads; 255 steps; FOUR barriers/step (R12 structure).
// R15 = exact R12 baseline + ONE change: giall L2-warm at init.
//   Rationale: R13-vs-R14 within-bundle A/B measured warm = -48us (190cy/step)
//   on the combine->gi chain; warm costs ZERO registers (the R13 bundle's
//   regression was scratch spill from 8 extra persistent VGPRs at the 128-VGPR
//   allocation boundary: VALUBusy fell, WRITE_SIZE +384KB, FETCH flat).
//   DO NOT add persistent per-thread state to this kernel - it spills.

__global__ __launch_bounds__(512, 2) void decode_kernel(
    const float* __restrict__ emb,
    const float* __restrict__ keysE, const float* __restrict__ giall,
    const float* __restrict__ Whh, const float* __restrict__ bhh,
    const float* __restrict__ Wq1, const float* __restrict__ bq1,
    const float* __restrict__ Wq2, const float* __restrict__ bq2,
    const float* __restrict__ v,   const float* __restrict__ Wh,
    const float* __restrict__ bh,  const int* __restrict__ start_nodes,
    float* __restrict__ tours_o, float* __restrict__ lp_o)
{
  __shared__ __align__(16) float keys_s[128*KSTRIDE];  // 132 KB, transposed E-keys
  __shared__ __align__(16) float h_s[2][160];          // staggered (H2A)
  __shared__ __align__(16) float qh_s[160];            // staggered (H2A)
  __shared__ __align__(16) float q_s[160];             // PAD16 (raw q), also gctx scratch
  __shared__ __align__(16) float v_sp[160];            // PAD16 layout, -2*v
  __shared__ __align__(16) float spartS[8*SSTR];       // score partials (+init scratch)
  __shared__ int col2node_s[256], node2col_s[256];
  __shared__ float red2[8];

  const int t = threadIdx.x;
  const int b = blockIdx.x;
  const int g  = t >> 2, s3 = t & 3;   // 128 groups x 4 lanes (matvec)
  const int w  = t >> 6, L  = t & 63;
  const int oct = L & 7, dgrp = L >> 3; // score: col-octet, dim-group

  // register weights: Whh rows g,128+g,256+g (chunk s3*32); Wq1/Wq2 row g
  float4 whh4[3][8], wq14[8], wq24[8];
  {
    const float4* w0  = (const float4*)(Whh + (size_t)(g      )*128 + s3*32);
    const float4* w1  = (const float4*)(Whh + (size_t)(128 + g)*128 + s3*32);
    const float4* w2  = (const float4*)(Whh + (size_t)(256 + g)*128 + s3*32);
    const float4* q1p = (const float4*)(Wq1 + (size_t)g*128 + s3*32);
    const float4* q2p = (const float4*)(Wq2 + (size_t)g*128 + s3*32);
    #pragma unroll
    for (int i=0;i<8;i++){
      whh4[0][i]=w0[i]; whh4[1][i]=w1[i]; whh4[2][i]=w2[i];
      wq14[i]=q1p[i];   wq24[i]=q2p[i];
    }
  }
  const float br = bhh[g], bz = bhh[128+g], bn = bhh[256+g];
  const float b1g = bq1[g], b2g = bq2[g];

  if (t<128) v_sp[PAD16(t)] = -2.f * v[t];
  if (t<256){ col2node_s[t] = t; node2col_s[t] = t; }
  { // stage transposed E-keys: coalesced per d-row
    #pragma unroll
    for (int m=0;m<16;m++){
      int idx = m*512 + t; int d = idx>>6, q = idx&63;
      *(float4*)(keys_s + d*KSTRIDE + q*4) =
        *(const float4*)(keysE + (size_t)d*TTOT + b*256 + q*4);
    }
  }
  { // graph-context partial sums (4 parts x 64 nodes)
    int d = t & 127, part = t >> 7;
    float a = 0.f;
    const float* base = emb + (size_t)(b*256 + part*64)*128 + d;
    for (int i=0;i<64;i++) a += base[(size_t)i*128];
    spartS[part*128+d] = a;
  }
  { // L2-warm this graph's giall slice (393KB/block; 4 blocks/XCD << 4MB L2).
    // Measured -48us within R13/R14 A/B: promotes MALL-resident gi rows into
    // the block's own XCD L2 so the per-step combine->gi load is ~L2 latency.
    // Zero persistent registers; asm sink prevents DCE (rule #17).
    const float4* gw = (const float4*)(giall + (size_t)b*256*384);
    float wx=0.f, wy=0.f, wz=0.f, ww=0.f;
    #pragma unroll 4
    for (int i=t; i<24576; i+=512){
      float4 xq = gw[i];
      wx+=xq.x; wy+=xq.y; wz+=xq.z; ww+=xq.w;
    }
    asm volatile("" :: "v"(wx), "v"(wy), "v"(wz), "v"(ww));
  }
  int cur = start_nodes[b];
  __syncthreads();
  if (t<128){
    float a = 0.f;
    #pragma unroll
    for (int p=0;p<4;p++) a += spartS[p*128+t];
    q_s[t] = a * (1.f/256.f);          // gctx temp (plain idx, init only)
  }
  __syncthreads();
  if (t<128){ // hidden0 = gctx@Wh.T + bh  (write staggered)
    float a = bh[t];
    const float* wr = Wh + (size_t)t*128;
    for (int k=0;k<128;k++) a += wr[k]*q_s[k];
    h_s[0][H2A(t)] = a;
  }
  { // sv = sum(v)
    float xv = (t<128) ? v[t] : 0.f;
    float tot = dpp_wave_sum(xv);
    if (L==0) red2[w] = tot;
  }
  __syncthreads();
  float sv = 0.f;
  #pragma unroll
  for (int i=0;i<8;i++) sv += red2[i];

  // gi prefetch for step 0
  float gir=0.f, giz=0.f, gin=0.f;
  if (s3==0){
    const float* gp = giall + (size_t)cur*384 + g;
    gir = gp[0]; giz = gp[128]; gin = gp[256];
  }

  for (int step=0; step<255; step++){
    const int par = step & 1;
    const int V   = 255 - step;          // valid count after removing cur
    const int curl = cur - b*256;

    // ---- swap-remove cur's keys column (waves 2-3; reads PRE-update map) ----
    if (t >= 128 && t < 256){
      int r = t - 128;
      int px = node2col_s[curl];
      keys_s[r*KSTRIDE + px] = keys_s[r*KSTRIDE + V];
    }
    if (t == 384) tours_o[b*256+step] = (float)cur;   // wave 6

    // ---- phase A: gh dots + fused GRU -> h_s[par^1] ----
    {
      float a0=0.f,a1=0.f,a2=0.f;
      const float4* hc4 = (const float4*)(h_s[par] + s3*40);
      #pragma unroll
      for (int i=0;i<8;i++){
        float4 hv = hc4[i];
        a0 += dot4(whh4[0][i], hv);
        a1 += dot4(whh4[1][i], hv);
        a2 += dot4(whh4[2][i], hv);
      }
      a0 = quad_sum_dpp(a0);
      a1 = quad_sum_dpp(a1);
      a2 = quad_sum_dpp(a2);
      if (s3==0){
        float r = sigfast(gir + a0 + br);
        float z = sigfast(giz + a1 + bz);
        float n = tanhfast(gin + r*(a2 + bn));
        h_s[par^1][H2A(g)] = (1.f-z)*n + z*h_s[par][H2A(g)];
      }
    }
    __syncthreads();                                   // B1

    // ---- deferred index-map update (wave 7; race-free: all prev-step
    //      combine reads of col2node_s completed before B1) ----
    if (t == 448){
      int px = node2col_s[curl];
      int ln = col2node_s[V];
      col2node_s[px] = ln;
      node2col_s[ln] = px;
    }

    { // qh = relu(h@Wq1.T + bq1)
      float a=0.f;
      const float4* hc4 = (const float4*)(h_s[par^1] + s3*40);
      #pragma unroll
      for (int i=0;i<8;i++) a += dot4(wq14[i], hc4[i]);
      a = quad_sum_dpp(a);
      if (s3==0) qh_s[H2A(g)] = fmaxf(a + b1g, 0.f);
    }
    __syncthreads();                                   // B2

    { // q_raw = qh@Wq2.T + bq2 (PAD16 store) ; per-wave ssq via DPP
      float a=0.f;
      const float4* qc4 = (const float4*)(qh_s + s3*40);
      #pragma unroll
      for (int i=0;i<8;i++) a += dot4(wq24[i], qc4[i]);
      a = quad_sum_dpp(a);
      float qval = a + b2g;
      if (s3==0) q_s[PAD16(g)] = qval;
      float ssp = (s3==0) ? qval*qval : 0.f;
      float tot = dpp_wave_sum(ssp);
      if (L==0) red2[w] = tot;
    }
    __syncthreads();                                   // B3

    // ---- score: wave w -> cols 32w..32w+31 (whole-wave skip when 32w >= V);
    //      rn/eq computed inline (B3b eliminated) ----
    if (32*w < V){
      float ss = 0.f;
      #pragma unroll
      for (int i=0;i<8;i++) ss += red2[i];
      float rn = 1.f / fmaxf(sqrtf(ss), 1e-12f);
      const float* kbase = keys_s + dgrp*16*KSTRIDE + 32*w + oct*4;
      const float* qb    = q_s  + dgrp*20;
      const float* vbase = v_sp + dgrp*20;
      float4 acc = {0.f,0.f,0.f,0.f};
      #pragma unroll
      for (int jj=0;jj<16;jj++){
        float eqj = __builtin_amdgcn_exp2f(qb[jj] * rn * LOG2E2);
        float vj  = vbase[jj];
        float4 K = *(const float4*)(kbase + jj*KSTRIDE);
        float r0 = __builtin_amdgcn_rcpf(fmaf(K.x, eqj, 1.f));
        float r1 = __builtin_amdgcn_rcpf(fmaf(K.y, eqj, 1.f));
        float r2 = __builtin_amdgcn_rcpf(fmaf(K.z, eqj, 1.f));
        float r3 = __builtin_amdgcn_rcpf(fmaf(K.w, eqj, 1.f));
        acc.x = fmaf(vj, r0, acc.x);
        acc.y = fmaf(vj, r1, acc.y);
        acc.z = fmaf(vj, r2, acc.z);
        acc.w = fmaf(vj, r3, acc.w);
      }
      *(float4*)(spartS + dgrp*SSTR + 32*w + oct*4) = acc;
    }
    __syncthreads();                                   // Bs1

    // ---- redundant combine: EVERY wave reduces all 256 cols; every lane
    //      learns argmax + softmax sum -> no Bs2, no tail round-trip ----
    {
      const float* sp = spartS + 4*L;
      float sx=0.f, sy=0.f, sz=0.f, sw=0.f;
      #pragma unroll
      for (int i=0;i<8;i++){
        float4 p = *(const float4*)(sp + i*SSTR);
        sx += p.x; sy += p.y; sz += p.z; sw += p.w;
      }
      int c0 = 4*L;
      float vx = (c0+0 < V) ? sv+sx : -INFINITY;
      float vy = (c0+1 < V) ? sv+sy : -INFINITY;
      float vz = (c0+2 < V) ? sv+sz : -INFINITY;
      float vw = (c0+3 < V) ? sv+sw : -INFINITY;
      float bm = vx; int bc = c0;                 // first-max tie-break
      if (vy > bm){ bm=vy; bc=c0+1; }
      if (vz > bm){ bm=vz; bc=c0+2; }
      if (vw > bm){ bm=vw; bc=c0+3; }
      float m = dpp_wave_max(bm);
      unsigned long long mk = __ballot(bm == m);
      int flane = __ffsll(mk) - 1;                // lowest lane = lowest col
      int besti = __builtin_amdgcn_readlane(bc, flane);
      float es = __builtin_amdgcn_exp2f((vx-m)*LOG2E) + __builtin_amdgcn_exp2f((vy-m)*LOG2E)
               + __builtin_amdgcn_exp2f((vz-m)*LOG2E) + __builtin_amdgcn_exp2f((vw-m)*LOG2E);
      float S = dpp_wave_sum(es);
      cur = b*256 + col2node_s[besti];            // read pre-next-update map
      if (s3==0){   // prefetch next gi (consumed in next phase A)
        const float* gp = giall + (size_t)cur*384 + g;
        gir = gp[0]; giz = gp[128]; gin = gp[256];
      }
      if (t==320) lp_o[b*255+step] = logf(1.f/S + 1e-10f);  // wave 5
    }
    // no barrier: next step's keys-swap/phase-A touch no combine-read state
  }
  if (t==0) tours_o[b*256+255] = (float)cur;

  (void)oct;
}

extern "C" void kernel_launch(void* const* d_in, const int* in_sizes, int n_in,
                              void* d_out, int out_size, void* d_ws, size_t ws_size,
                              hipStream_t stream) {
  const float* emb  = (const float*)d_in[0];
  const int*   startn = (const int*)d_in[1];
  const float* Wq1 = (const float*)d_in[3];  const float* bq1 = (const float*)d_in[4];
  const float* Wq2 = (const float*)d_in[5];  const float* bq2 = (const float*)d_in[6];
  const float* Wk1 = (const float*)d_in[7];  const float* bk1 = (const float*)d_in[8];
  const float* Wk2 = (const float*)d_in[9];  const float* bk2 = (const float*)d_in[10];
  const float* Wih = (const float*)d_in[11]; const float* Whh = (const float*)d_in[12];
  const float* bih = (const float*)d_in[13]; const float* bhh = (const float*)d_in[14];
  const float* v   = (const float*)d_in[15]; const float* Wh  = (const float*)d_in[16];
  const float* bh  = (const float*)d_in[17];

  float* keysE = (float*)d_ws;               // exp(2*keys) TRANSPOSED [128][8192]
  float* giall = keysE + (size_t)TTOT*DD;    // [8192*384]

  float* outp = (float*)d_out;   // tours [32*256] then log_probs [32*255]

  precompute_kernel<<<256, 256, 0, stream>>>(emb, Wk1, bk1, Wk2, bk2, Wih, bih, keysE, giall);
  decode_kernel<<<NGR, 512, 0, stream>>>(emb, keysE, giall, Whh, bhh, Wq1, bq1, Wq2, bq2,
                                         v, Wh, bh, startn, outp, outp + TTOT);
}